// Round 8
// baseline (289.329 us; speedup 1.0000x reference)
//
#include <hip/hip_runtime.h>
#include <hip/hip_bf16.h>

#define N_ROWS 4096
#define TWO_N 8192
#define DIM 512
#define NBLK 2080
#define INV_T 14.285714285714286f          // 1/0.07
#define LOG2E 1.4426950408889634f
#define C_LOG2E 20.60992915555662f          // (1/0.07)*log2(e)
#define INV_SQRT_T 3.7796447300922722f      // 1/sqrt(0.07)

typedef __bf16 bf16x8 __attribute__((ext_vector_type(8)));
typedef float f32x4 __attribute__((ext_vector_type(4)));

#define ASYNC_COPY16(gp, lp)                                                     \
  __builtin_amdgcn_global_load_lds((const __attribute__((address_space(1))) void*)(gp), \
                                   (__attribute__((address_space(3))) void*)(lp), 16, 0, 0)

// Vectorized prep: 2048 blocks, 2 rows per block. float4 loads, uint2 stores.
// Also zeroes rowsum and the completion counter.
__global__ void k_prep(const float* __restrict__ z1, const float* __restrict__ z2,
                       __hip_bfloat16* __restrict__ zn, float* __restrict__ posbuf,
                       float* __restrict__ rowsum, unsigned int* __restrict__ ctr) {
  __shared__ float red[4][3];
  const int t = threadIdx.x;
  if (blockIdx.x < 32) rowsum[blockIdx.x * 256 + t] = 0.f;
  if (blockIdx.x == 0 && t == 0) ctr[0] = 0u;
  const int half = t >> 7;              // 0 or 1
  const int tt = t & 127;
  const int r = blockIdx.x * 2 + half;
  const float4 a = *reinterpret_cast<const float4*>(z1 + (size_t)r * DIM + tt * 4);
  const float4 b = *reinterpret_cast<const float4*>(z2 + (size_t)r * DIM + tt * 4);
  float s1 = a.x * a.x + a.y * a.y + a.z * a.z + a.w * a.w;
  float s2 = b.x * b.x + b.y * b.y + b.z * b.z + b.w * b.w;
  float sd = a.x * b.x + a.y * b.y + a.z * b.z + a.w * b.w;
#pragma unroll
  for (int off = 32; off > 0; off >>= 1) {
    s1 += __shfl_down(s1, off, 64);
    s2 += __shfl_down(s2, off, 64);
    sd += __shfl_down(sd, off, 64);
  }
  const int w = t >> 6;
  if ((t & 63) == 0) { red[w][0] = s1; red[w][1] = s2; red[w][2] = sd; }
  __syncthreads();
  s1 = red[2 * half][0] + red[2 * half + 1][0];
  s2 = red[2 * half][1] + red[2 * half + 1][1];
  sd = red[2 * half][2] + red[2 * half + 1][2];
  const float sc1 = INV_SQRT_T / fmaxf(sqrtf(s1), 1e-8f);
  const float sc2 = INV_SQRT_T / fmaxf(sqrtf(s2), 1e-8f);
  union { __hip_bfloat16 h[4]; uint2 u; } p;
  p.h[0] = __float2bfloat16(a.x * sc1); p.h[1] = __float2bfloat16(a.y * sc1);
  p.h[2] = __float2bfloat16(a.z * sc1); p.h[3] = __float2bfloat16(a.w * sc1);
  *reinterpret_cast<uint2*>(zn + (size_t)r * DIM + tt * 4) = p.u;
  p.h[0] = __float2bfloat16(b.x * sc2); p.h[1] = __float2bfloat16(b.y * sc2);
  p.h[2] = __float2bfloat16(b.z * sc2); p.h[3] = __float2bfloat16(b.w * sc2);
  *reinterpret_cast<uint2*>(zn + (size_t)(r + N_ROWS) * DIM + tt * 4) = p.u;
  if (tt == 0) posbuf[r] = sd * sc1 * sc2;   // = cos(z1_r,z2_r)/T
}

// Flash-LSE GEMM, 128x128 tile, upper-triangle (rt<=ct), BK=64 double-buffered.
// LDS: 2 bufs x (A 128x64 bf16 = 16KB + B 16KB) = 64KB. Row = 128B = 8 granules
// of 16B; granule rotation swizzle (g + row) & 7 -> 2-way (free) LDS phases.
// 8 K-iters (vs 16 at BK=32): half the barrier-drain events, same bytes.
// Off-diag tiles: row-sums -> rt rows, col-sums -> ct rows. Diag tiles: row only.
// Last block (atomic counter) does the final log/pos reduction.
__global__ __launch_bounds__(256, 2) void k_lse(const __hip_bfloat16* __restrict__ Zn,
                                                float* __restrict__ rowsum,
                                                const float* __restrict__ posbuf,
                                                unsigned int* __restrict__ ctr,
                                                float* __restrict__ out) {
  __shared__ char smem[65536] __attribute__((aligned(16)));
  const int tid  = threadIdx.x;
  const int wave = tid >> 6;
  const int lane = tid & 63;
  const int cl   = lane & 15;
  const int q    = lane >> 4;

  // linear b -> (rt, ct) with rt <= ct over 64x64 tile grid (verified R3/R4)
  const int b = blockIdx.x;
  int rt = (int)((129.0f - sqrtf(16641.0f - 8.0f * (float)b)) * 0.5f);
  if (rt > 63) rt = 63;
  if (rt < 0) rt = 0;
  while (rt > 0 && 64 * rt - rt * (rt - 1) / 2 > b) rt--;
  while (64 * (rt + 1) - (rt + 1) * rt / 2 <= b) rt++;
  const int ct = rt + (b - (64 * rt - rt * (rt - 1) / 2));

  const int wr = (wave >> 1) * 64;   // wave's row offset in tile
  const int wc = (wave & 1) * 64;    // wave's col offset in tile

  // Staging: A tile = 1024 granules (slots). Slot s: row = s>>3, holds data
  // granule gd = ((s&7) - row) & 7. Thread t owns slots t + c*256, c=0..3.
  unsigned int ga[4], gb[4];
#pragma unroll
  for (int c = 0; c < 4; c++) {
    const int s = tid + c * 256;
    const int r = s >> 3;
    const int gd = ((s & 7) - r) & 7;
    ga[c] = (unsigned int)((rt * 128 + r) * DIM + gd * 8);
    gb[c] = (unsigned int)((ct * 128 + r) * DIM + gd * 8);
  }

  f32x4 acc[4][4] = {};

#define STAGE(bufi, ko)                                                        \
  {                                                                            \
    char* dA = smem + (bufi) * 32768 + wave * 1024;                            \
    char* dB = dA + 16384;                                                     \
    ASYNC_COPY16(Zn + ga[0] + (ko), dA);                                       \
    ASYNC_COPY16(Zn + ga[1] + (ko), dA + 4096);                                \
    ASYNC_COPY16(Zn + ga[2] + (ko), dA + 8192);                                \
    ASYNC_COPY16(Zn + ga[3] + (ko), dA + 12288);                               \
    ASYNC_COPY16(Zn + gb[0] + (ko), dB);                                       \
    ASYNC_COPY16(Zn + gb[1] + (ko), dB + 4096);                                \
    ASYNC_COPY16(Zn + gb[2] + (ko), dB + 8192);                                \
    ASYNC_COPY16(Zn + gb[3] + (ko), dB + 12288);                               \
  }

  STAGE(0, 0);
  for (int ks = 0; ks < DIM / 64; ks++) {
    const int cur = ks & 1;
    __syncthreads();                      // drains copy issued last iteration
    if (ks + 1 < DIM / 64) STAGE(1 - cur, (ks + 1) * 64);

    const char* sA = smem + cur * 32768;
    const char* sB = sA + 16384;
#pragma unroll
    for (int ss = 0; ss < 2; ss++) {      // two K=32 sub-steps within BK=64
      bf16x8 af[4], bfr[4];
#pragma unroll
      for (int i = 0; i < 4; i++) {
        const int r = wr + i * 16 + cl;
        af[i] = *reinterpret_cast<const bf16x8*>(sA + r * 128 + ((ss * 4 + q + r) & 7) * 16);
      }
#pragma unroll
      for (int j = 0; j < 4; j++) {
        const int r = wc + j * 16 + cl;
        bfr[j] = *reinterpret_cast<const bf16x8*>(sB + r * 128 + ((ss * 4 + q + r) & 7) * 16);
      }
#pragma unroll
      for (int i = 0; i < 4; i++)
#pragma unroll
        for (int j = 0; j < 4; j++)
          acc[i][j] = __builtin_amdgcn_mfma_f32_16x16x32_bf16(af[i], bfr[j], acc[i][j], 0, 0, 0);
    }
  }
#undef STAGE

  // Epilogue: e = exp(s - C) with diagonal masked.
  // C-layout: col = cl, row = q*4 + r (within 16x16 frag (i,j)).
  const bool diagw = (rt == ct) && (wr == wc);
  float psum[4][4];
#pragma unroll
  for (int i = 0; i < 4; i++)
#pragma unroll
    for (int r = 0; r < 4; r++) psum[i][r] = 0.f;
  float colp[4] = {0.f, 0.f, 0.f, 0.f};

#pragma unroll
  for (int i = 0; i < 4; i++)
#pragma unroll
    for (int j = 0; j < 4; j++)
#pragma unroll
      for (int r = 0; r < 4; r++) {
        float e = exp2f(fmaf(acc[i][j][r], LOG2E, -C_LOG2E));
        if (diagw && (i == j) && (cl == q * 4 + r)) e = 0.f;
        psum[i][r] += e;
        colp[j] += e;
      }

  // row sums -> rt rows (reduce across cols: cl lanes)
#pragma unroll
  for (int i = 0; i < 4; i++)
#pragma unroll
    for (int r = 0; r < 4; r++) {
      float v = psum[i][r];
      v += __shfl_xor(v, 1, 64);
      v += __shfl_xor(v, 2, 64);
      v += __shfl_xor(v, 4, 64);
      v += __shfl_xor(v, 8, 64);
      if (cl == 0) atomicAdd(&rowsum[rt * 128 + wr + i * 16 + q * 4 + r], v);
    }

  // col sums -> ct rows (reduce across rows: q lanes), only off-diagonal tiles
  if (rt != ct) {
#pragma unroll
    for (int j = 0; j < 4; j++) {
      float v = colp[j];
      v += __shfl_xor(v, 16, 64);
      v += __shfl_xor(v, 32, 64);
      if (q == 0) atomicAdd(&rowsum[ct * 128 + wc + j * 16 + cl], v);
    }
  }

  // ---- fused finalize: last block reduces ----
  __threadfence();
  __syncthreads();
  __shared__ int is_last;
  if (tid == 0) {
    unsigned int prev = __hip_atomic_fetch_add(ctr, 1u, __ATOMIC_ACQ_REL,
                                               __HIP_MEMORY_SCOPE_AGENT);
    is_last = (prev == NBLK - 1) ? 1 : 0;
  }
  __syncthreads();
  if (is_last) {
    float s = 0.f;
    for (int r = tid; r < TWO_N; r += 256) {
      float v = __hip_atomic_load(&rowsum[r], __ATOMIC_RELAXED,
                                  __HIP_MEMORY_SCOPE_AGENT);
      s += logf(v);
    }
    for (int r = tid; r < N_ROWS; r += 256) s -= 2.f * posbuf[r];
#pragma unroll
    for (int off = 32; off > 0; off >>= 1) s += __shfl_down(s, off, 64);
    float* red = reinterpret_cast<float*>(smem);
    if ((tid & 63) == 0) red[tid >> 6] = s;
    __syncthreads();
    if (tid == 0)
      out[0] = (red[0] + red[1] + red[2] + red[3]) / (float)TWO_N + INV_T;
  }
}

extern "C" void kernel_launch(void* const* d_in, const int* in_sizes, int n_in,
                              void* d_out, int out_size, void* d_ws, size_t ws_size,
                              hipStream_t stream) {
  const float* z1 = (const float*)d_in[0];
  const float* z2 = (const float*)d_in[1];
  float* out = (float*)d_out;
  char* ws = (char*)d_ws;

  __hip_bfloat16* zn = (__hip_bfloat16*)ws;              // 8192*512*2 = 8388608 B
  float* rowsum = (float*)(ws + 8388608);                 // 8192*4 = 32768 B
  float* posbuf = (float*)(ws + 8421376);                 // 4096*4 = 16384 B
  unsigned int* ctr = (unsigned int*)(ws + 8437760);      // 4 B

  k_prep<<<2048, 256, 0, stream>>>(z1, z2, zn, posbuf, rowsum, ctr);
  k_lse<<<NBLK, 256, 0, stream>>>(zn, rowsum, posbuf, ctr, out);
}